// Round 1
// baseline (1088.631 us; speedup 1.0000x reference)
//
#include <hip/hip_runtime.h>
#include <math.h>

#define BB 8
#define HH 8
#define SS 1024
#define DD 64
#define BH (BB * HH)

// ---------------------------------------------------------------------------
// K1: raw logits for the causal (lower-triangular) tiles.
// logits[i,j] = sum_d q[i,d] * (k[j,d] + RK[clamp(j-i+512,0,512), d])
// Tile: 16 rows (i) x 64 cols (j). Block = 256 threads.
// ---------------------------------------------------------------------------
__global__ __launch_bounds__(256) void k_logits(const float* __restrict__ q,
                                                const float* __restrict__ k,
                                                const float* __restrict__ RK,
                                                float* __restrict__ Wout) {
  const int j0 = blockIdx.x * 64;
  const int i0 = blockIdx.y * 16;
  const int bh = blockIdx.z;
  const int i_end = i0 + 15;
  if (j0 > i_end) return;  // tile fully masked; K2 writes the zeros

  // stride 68 floats = 272 B: 16B-aligned rows, bank-stride 4 (conflict-light)
  __shared__ __align__(16) float qs[16][68];
  __shared__ __align__(16) float ks[64][68];
  __shared__ __align__(16) float rks[79][68];

  const int t = threadIdx.x;

  // stage q tile (16x64 contiguous floats)
  {
    const float4* src = (const float4*)(q + ((size_t)bh * SS + i0) * DD);
    const int rr = t >> 4, c4 = t & 15;
    *(float4*)&qs[rr][c4 * 4] = src[t];
  }
  // stage k tile (64x64)
  {
    const float4* src = (const float4*)(k + ((size_t)bh * SS + j0) * DD);
#pragma unroll
    for (int m = 0; m < 4; ++m) {
      const int idx = t + 256 * m;
      const int rr = idx >> 4, c4 = idx & 15;
      *(float4*)&ks[rr][c4 * 4] = src[idx];
    }
  }
  // stage RK rows: u in [0,78] maps to p = clamp(pLo + u, 0, 512)
  {
    const int pLo = j0 - i_end + 512;
    for (int idx = t; idx < 79 * 16; idx += 256) {
      const int u = idx >> 4, c4 = idx & 15;
      int p = pLo + u;
      p = p < 0 ? 0 : (p > 512 ? 512 : p);
      *(float4*)&rks[u][c4 * 4] = *(const float4*)(RK + (size_t)p * DD + c4 * 4);
    }
  }
  __syncthreads();

  const int r = t >> 4;   // row within tile
  const int jc = t & 15;  // col group: cols j = jc + 16*c
  float acc[4] = {0.f, 0.f, 0.f, 0.f};

#pragma unroll 4
  for (int d4 = 0; d4 < 16; ++d4) {
    const float4 q4 = *(const float4*)&qs[r][d4 * 4];
#pragma unroll
    for (int c = 0; c < 4; ++c) {
      const int jj = jc + 16 * c;
      const float4 k4 = *(const float4*)&ks[jj][d4 * 4];
      const float4 rk4 = *(const float4*)&rks[jj + 15 - r][d4 * 4];
      acc[c] += q4.x * (k4.x + rk4.x);
      acc[c] += q4.y * (k4.y + rk4.y);
      acc[c] += q4.z * (k4.z + rk4.z);
      acc[c] += q4.w * (k4.w + rk4.w);
    }
  }

  const size_t rowBase = ((size_t)bh * SS + (size_t)(i0 + r)) * SS + j0;
#pragma unroll
  for (int c = 0; c < 4; ++c) Wout[rowBase + jc + 16 * c] = acc[c];
}

// ---------------------------------------------------------------------------
// K2: exact softmax per row, in place. Writes full rows (0 for masked j > i).
// One block (256 threads) per (bh, i).
// ---------------------------------------------------------------------------
__global__ __launch_bounds__(256) void k_softmax(float* __restrict__ Wbuf) {
  const int i = blockIdx.x;
  const int bh = blockIdx.y;
  float* row = Wbuf + ((size_t)bh * SS + i) * SS;
  const int t = threadIdx.x;

  float vv[4];
  float m = -INFINITY;
#pragma unroll
  for (int c = 0; c < 4; ++c) {
    const int j = t + 256 * c;
    vv[c] = (j <= i) ? row[j] : -INFINITY;
    m = fmaxf(m, vv[c]);
  }
#pragma unroll
  for (int off = 32; off > 0; off >>= 1) m = fmaxf(m, __shfl_xor(m, off));

  __shared__ float red[8];
  const int wid = t >> 6;
  if ((t & 63) == 0) red[wid] = m;
  __syncthreads();
  m = fmaxf(fmaxf(red[0], red[1]), fmaxf(red[2], red[3]));

  float s = 0.f;
#pragma unroll
  for (int c = 0; c < 4; ++c) {
    const int j = t + 256 * c;
    vv[c] = (j <= i) ? __expf(vv[c] - m) : 0.f;
    s += vv[c];
  }
#pragma unroll
  for (int off = 32; off > 0; off >>= 1) s += __shfl_xor(s, off);
  if ((t & 63) == 0) red[4 + wid] = s;  // disjoint from red[0..3]: no race
  __syncthreads();
  const float inv = 1.f / (red[4] + red[5] + red[6] + red[7]);

#pragma unroll
  for (int c = 0; c < 4; ++c) row[t + 256 * c] = vv[c] * inv;
}

// ---------------------------------------------------------------------------
// K3: O[i,d] = sum_j w[i,j] * (v[j,d] + RV[clamp(j-i+512,0,512), d]).
// Masked w are exactly 0, so no per-row guards needed.
// Tile: 16 rows (i), j in chunks of 64. Block = 256 threads.
// ---------------------------------------------------------------------------
__global__ __launch_bounds__(256) void k_out(const float* __restrict__ Wbuf,
                                             const float* __restrict__ v,
                                             const float* __restrict__ RV,
                                             float* __restrict__ Out) {
  const int i0 = blockIdx.x * 16;
  const int bh = blockIdx.y;
  const int i_end = i0 + 15;

  __shared__ __align__(16) float ws[16][68];
  __shared__ __align__(16) float vs[64][68];
  __shared__ __align__(16) float rvs[79][68];

  const int t = threadIdx.x;
  const int r = t >> 4;   // row within tile
  const int dc = t & 15;  // d group: d = dc*4 + {0..3}
  float4 acc = {0.f, 0.f, 0.f, 0.f};

  for (int j0 = 0; j0 <= i_end; j0 += 64) {
    // stage w tile 16x64
    {
      const int rr = t >> 4, c4 = t & 15;
      *(float4*)&ws[rr][c4 * 4] =
          *(const float4*)(Wbuf + ((size_t)bh * SS + (size_t)(i0 + rr)) * SS + j0 + c4 * 4);
    }
    // stage v tile 64x64
    {
      const float4* src = (const float4*)(v + ((size_t)bh * SS + j0) * DD);
#pragma unroll
      for (int m = 0; m < 4; ++m) {
        const int idx = t + 256 * m;
        const int rr = idx >> 4, c4 = idx & 15;
        *(float4*)&vs[rr][c4 * 4] = src[idx];
      }
    }
    // stage RV rows
    {
      const int pLo = j0 - i_end + 512;
      for (int idx = t; idx < 79 * 16; idx += 256) {
        const int u = idx >> 4, c4 = idx & 15;
        int p = pLo + u;
        p = p < 0 ? 0 : (p > 512 ? 512 : p);
        *(float4*)&rvs[u][c4 * 4] = *(const float4*)(RV + (size_t)p * DD + c4 * 4);
      }
    }
    __syncthreads();

#pragma unroll 4
    for (int j = 0; j < 64; ++j) {
      const float wv = ws[r][j];
      const float4 v4 = *(const float4*)&vs[j][dc * 4];
      const float4 rv4 = *(const float4*)&rvs[j + 15 - r][dc * 4];
      acc.x += wv * (v4.x + rv4.x);
      acc.y += wv * (v4.y + rv4.y);
      acc.z += wv * (v4.z + rv4.z);
      acc.w += wv * (v4.w + rv4.w);
    }
    __syncthreads();
  }

  *(float4*)(Out + ((size_t)bh * SS + (size_t)(i0 + r)) * DD + dc * 4) = acc;
}

extern "C" void kernel_launch(void* const* d_in, const int* in_sizes, int n_in,
                              void* d_out, int out_size, void* d_ws, size_t ws_size,
                              hipStream_t stream) {
  const float* q = (const float*)d_in[0];
  const float* k = (const float*)d_in[1];
  const float* v = (const float*)d_in[2];
  const float* RK = (const float*)d_in[3];  // (1025, 64); only rows 0..512 used
  const float* RV = (const float*)d_in[4];
  // d_in[5] (rel_positions) and d_in[6] (mask) are deterministic; recomputed on the fly.

  float* O = (float*)d_out;                       // (B,H,S,D) = 4194304 floats
  float* W = (float*)d_out + (size_t)BH * SS * DD;  // (B,H,S,S) = 67108864 floats

  k_logits<<<dim3(SS / 64, SS / 16, BH), 256, 0, stream>>>(q, k, RK, W);
  k_softmax<<<dim3(SS, BH), 256, 0, stream>>>(W);
  k_out<<<dim3(SS / 16, BH), 256, 0, stream>>>(W, v, RV, O);
}

// Round 2
// 711.229 us; speedup vs baseline: 1.5306x; 1.5306x over previous
//
#include <hip/hip_runtime.h>
#include <math.h>

#define SS 1024
#define DD 64
#define BH 64

typedef __attribute__((ext_vector_type(4))) float fx4;
typedef __attribute__((ext_vector_type(8))) short sx8;
typedef __attribute__((ext_vector_type(4))) short sx4;

__device__ __forceinline__ unsigned short f2bf(float x) {
  unsigned u = __builtin_bit_cast(unsigned, x);
  u += 0x7fffu + ((u >> 16) & 1u);
  return (unsigned short)(u >> 16);
}
__device__ __forceinline__ float bf2f(unsigned short h) {
  return __builtin_bit_cast(float, ((unsigned)h) << 16);
}

// ---------------------------------------------------------------------------
// Kernel A: raw logits via MFMA.
// logits[i,j] = q[i]·k[j]  (split bf16, 3 products)  +  q[i]·RK[p(i,j)] (bf16)
// Rel term: S2 = Q @ RKstaged^T then gather S2[r, 63+c-r] via __shfl.
// Block: 256 thr (4 waves), tile 64 rows (i) x 64 cols (j), loop over j-tiles.
// ---------------------------------------------------------------------------
__global__ __launch_bounds__(256) void k_logits_mfma(const float* __restrict__ q,
                                                     const float* __restrict__ k,
                                                     const float* __restrict__ RK,
                                                     float* __restrict__ W) {
  const int it = blockIdx.x, bh = blockIdx.y;
  const int i0 = it * 64;

  __shared__ __align__(16) short sQh[64 * 72];
  __shared__ __align__(16) short sQl[64 * 72];
  __shared__ __align__(16) short sKh[64 * 72];
  __shared__ __align__(16) short sKl[64 * 72];
  __shared__ __align__(16) short sRh[128 * 72];  // rel-key rows u=0..127

  const int t = threadIdx.x;
  const int lane = t & 63, mt = t >> 6, quad = lane >> 4, lc = lane & 15;

  // stage Q (hi/lo split)
  for (int idx = t; idx < 1024; idx += 256) {
    const int row = idx >> 4, c4 = (idx & 15) * 4;
    const float4 x = *(const float4*)(q + ((size_t)(bh * SS + i0 + row)) * DD + c4);
    const float xs[4] = {x.x, x.y, x.z, x.w};
    sx4 h, l;
#pragma unroll
    for (int e = 0; e < 4; ++e) {
      const unsigned short hb = f2bf(xs[e]);
      h[e] = (short)hb;
      l[e] = (short)f2bf(xs[e] - bf2f(hb));
    }
    *(sx4*)&sQh[row * 72 + c4] = h;
    *(sx4*)&sQl[row * 72 + c4] = l;
  }

  for (int jt = 0; jt <= it; ++jt) {
    const int j0 = jt * 64;
    __syncthreads();  // prev-tile frag reads done (also orders Q staging on jt=0)
    // stage K (hi/lo)
    for (int idx = t; idx < 1024; idx += 256) {
      const int row = idx >> 4, c4 = (idx & 15) * 4;
      const float4 x = *(const float4*)(k + ((size_t)(bh * SS + j0 + row)) * DD + c4);
      const float xs[4] = {x.x, x.y, x.z, x.w};
      sx4 h, l;
#pragma unroll
      for (int e = 0; e < 4; ++e) {
        const unsigned short hb = f2bf(xs[e]);
        h[e] = (short)hb;
        l[e] = (short)f2bf(xs[e] - bf2f(hb));
      }
      *(sx4*)&sKh[row * 72 + c4] = h;
      *(sx4*)&sKl[row * 72 + c4] = l;
    }
    // stage RK rows: u -> p = clamp(pLo+u, 0, 512)
    const int pLo = j0 - i0 - 63 + 512;
    for (int idx = t; idx < 2048; idx += 256) {
      const int u = idx >> 4, c4 = (idx & 15) * 4;
      int p = pLo + u;
      p = p < 0 ? 0 : (p > 512 ? 512 : p);
      const float4 x = *(const float4*)(RK + (size_t)p * DD + c4);
      sx4 h;
      h[0] = (short)f2bf(x.x); h[1] = (short)f2bf(x.y);
      h[2] = (short)f2bf(x.z); h[3] = (short)f2bf(x.w);
      *(sx4*)&sRh[u * 72 + c4] = h;
    }
    __syncthreads();

    const fx4 zz = {0.f, 0.f, 0.f, 0.f};
    fx4 accS1[4] = {zz, zz, zz, zz};
    fx4 accS2[5] = {zz, zz, zz, zz, zz};

#pragma unroll
    for (int ks = 0; ks < 2; ++ks) {
      const int koff = ks * 32 + quad * 8;
      const sx8 aQh = *(const sx8*)&sQh[(mt * 16 + lc) * 72 + koff];
      const sx8 aQl = *(const sx8*)&sQl[(mt * 16 + lc) * 72 + koff];
#pragma unroll
      for (int nt = 0; nt < 4; ++nt) {
        const sx8 bKh = *(const sx8*)&sKh[(nt * 16 + lc) * 72 + koff];
        const sx8 bKl = *(const sx8*)&sKl[(nt * 16 + lc) * 72 + koff];
        accS1[nt] = __builtin_amdgcn_mfma_f32_16x16x32_bf16(aQh, bKh, accS1[nt], 0, 0, 0);
        accS1[nt] = __builtin_amdgcn_mfma_f32_16x16x32_bf16(aQl, bKh, accS1[nt], 0, 0, 0);
        accS1[nt] = __builtin_amdgcn_mfma_f32_16x16x32_bf16(aQh, bKl, accS1[nt], 0, 0, 0);
      }
#pragma unroll
      for (int s = 0; s < 5; ++s) {  // wave mt needs absolute u-tiles (3-mt)..(7-mt)
        const sx8 bR = *(const sx8*)&sRh[((3 - mt + s) * 16 + lc) * 72 + koff];
        accS2[s] = __builtin_amdgcn_mfma_f32_16x16x32_bf16(aQh, bR, accS2[s], 0, 0, 0);
      }
    }

    // epilogue: logits = S1 + S2[r, u=63+c-r]; gather is an intra-quad lane rotate
#pragma unroll
    for (int nt = 0; nt < 4; ++nt) {
#pragma unroll
      for (int e = 0; e < 4; ++e) {
        const int rr = quad * 4 + e;
        const int du = 63 + lc - rr;  // in [48,78]; rel tile = nt + (du>>4) - 3
        const int srcLane = (lane & 48) | (du & 15);
        const float v0 = __shfl(accS2[nt][e], srcLane, 64);
        const float v1 = __shfl(accS2[nt + 1][e], srcLane, 64);
        const float val = accS1[nt][e] + (du < 64 ? v0 : v1);
        W[((size_t)(bh * SS + i0 + mt * 16 + rr)) * SS + j0 + nt * 16 + lc] = val;
      }
    }
  }
}

// ---------------------------------------------------------------------------
// Kernel B: fused softmax + output.
// Phase 0: zero masked upper tiles of W. Phase 1: per-row online max/sum.
// Phase 2: per j-tile: w = exp(x-m)/s (store to W), MFMA O += w@v + wskew@RVs.
// ---------------------------------------------------------------------------
__global__ __launch_bounds__(256) void k_soft_out(float* __restrict__ W,
                                                  const float* __restrict__ v,
                                                  const float* __restrict__ RV,
                                                  float* __restrict__ O) {
  const int it = blockIdx.x, bh = blockIdx.y;
  const int i0 = it * 64, iEnd = i0 + 63;

  __shared__ float rowM[64], rowInv[64];
  __shared__ __align__(16) short wA[64 * 72];     // w[r][c] bf16
  __shared__ __align__(16) short wSk[64 * 136];   // wskew[r][u]
  __shared__ __align__(16) short vT[64 * 72];     // v^T[d][j]
  __shared__ __align__(16) short rvT[64 * 136];   // RVstaged^T[d][u]

  const int t = threadIdx.x;
  const int lane = t & 63, mt = t >> 6, quad = lane >> 4, lc = lane & 15;
  const int r = t >> 2, g = t & 3;
  float* __restrict__ Wrow = W + ((size_t)(bh * SS + i0 + r)) * SS;
  const int iG = i0 + r;

  // phase 0: zero the fully-masked upper tiles
  for (int j = (it + 1) * 64 + g * 4; j < SS; j += 16) {
    float4 z; z.x = z.y = z.z = z.w = 0.f;
    *(float4*)(Wrow + j) = z;
  }

  // phase 1: online (max, sum) over valid cols; 4 threads per row
  float m = -1e30f, s = 0.f;
  for (int j = g * 4; j <= iEnd; j += 16) {
    const float4 x4 = *(const float4*)(Wrow + j);
    const float xs[4] = {x4.x, x4.y, x4.z, x4.w};
#pragma unroll
    for (int e = 0; e < 4; ++e) {
      const float x = (j + e <= iG) ? xs[e] : -1e30f;
      const float nm = fmaxf(m, x);
      s = s * __expf(m - nm) + __expf(x - nm);
      m = nm;
    }
  }
#pragma unroll
  for (int off = 1; off <= 2; off <<= 1) {
    const float mo = __shfl_xor(m, off, 64);
    const float so = __shfl_xor(s, off, 64);
    const float nm = fmaxf(m, mo);
    s = s * __expf(m - nm) + so * __expf(mo - nm);
    m = nm;
  }
  if (g == 0) { rowM[r] = m; rowInv[r] = 1.f / s; }
  __syncthreads();

  const fx4 zz = {0.f, 0.f, 0.f, 0.f};
  fx4 accO[4] = {zz, zz, zz, zz};

  for (int jt = 0; jt <= it; ++jt) {
    const int j0 = jt * 64;
    const int pLo = j0 - i0 - 63 + 512;
    if (jt) __syncthreads();  // prev-tile mfma reads done
    // zero wskew
    {
      sx8 z8 = {0, 0, 0, 0, 0, 0, 0, 0};
      for (int x = t; x < 1088; x += 256) *(sx8*)&wSk[x * 8] = z8;
    }
    __syncthreads();

    // w tile: read raw logits, softmax-normalize, write W, stage wA + wskew
    const float rm = rowM[r], ri = rowInv[r];
#pragma unroll
    for (int g4 = 0; g4 < 4; ++g4) {
      const int c = g * 4 + g4 * 16;
      const float4 x4 = *(const float4*)(Wrow + j0 + c);
      const float xs[4] = {x4.x, x4.y, x4.z, x4.w};
      float4 w4;
      sx4 hb;
      float* wp = &w4.x;
#pragma unroll
      for (int e = 0; e < 4; ++e) {
        const float w = (j0 + c + e <= iG) ? __expf(xs[e] - rm) * ri : 0.f;
        wp[e] = w;
        hb[e] = (short)f2bf(w);
      }
      *(float4*)(Wrow + j0 + c) = w4;
      *(sx4*)&wA[r * 72 + c] = hb;
      const int u0 = 63 + c - r;
#pragma unroll
      for (int e = 0; e < 4; ++e) wSk[r * 136 + u0 + e] = hb[e];
    }
    // stage v^T
    for (int idx = t; idx < 1024; idx += 256) {
      const int jj = idx >> 4, d4 = (idx & 15) * 4;
      const float4 x4 = *(const float4*)(v + ((size_t)(bh * SS + j0 + jj)) * DD + d4);
      vT[(d4 + 0) * 72 + jj] = (short)f2bf(x4.x);
      vT[(d4 + 1) * 72 + jj] = (short)f2bf(x4.y);
      vT[(d4 + 2) * 72 + jj] = (short)f2bf(x4.z);
      vT[(d4 + 3) * 72 + jj] = (short)f2bf(x4.w);
    }
    // stage RVstaged^T
    for (int idx = t; idx < 2048; idx += 256) {
      const int u = idx >> 4, d4 = (idx & 15) * 4;
      int p = pLo + u;
      p = p < 0 ? 0 : (p > 512 ? 512 : p);
      const float4 x4 = *(const float4*)(RV + (size_t)p * DD + d4);
      rvT[(d4 + 0) * 136 + u] = (short)f2bf(x4.x);
      rvT[(d4 + 1) * 136 + u] = (short)f2bf(x4.y);
      rvT[(d4 + 2) * 136 + u] = (short)f2bf(x4.z);
      rvT[(d4 + 3) * 136 + u] = (short)f2bf(x4.w);
    }
    __syncthreads();

    // O += w @ v   (K = 64 over j)
#pragma unroll
    for (int ks = 0; ks < 2; ++ks) {
      const int koff = ks * 32 + quad * 8;
      const sx8 aW = *(const sx8*)&wA[(mt * 16 + lc) * 72 + koff];
#pragma unroll
      for (int nt = 0; nt < 4; ++nt) {
        const sx8 bV = *(const sx8*)&vT[(nt * 16 + lc) * 72 + koff];
        accO[nt] = __builtin_amdgcn_mfma_f32_16x16x32_bf16(aW, bV, accO[nt], 0, 0, 0);
      }
    }
    // O += wskew @ RVstaged   (K = 128 over u)
#pragma unroll
    for (int ks = 0; ks < 4; ++ks) {
      const int koff = ks * 32 + quad * 8;
      const sx8 aS = *(const sx8*)&wSk[(mt * 16 + lc) * 136 + koff];
#pragma unroll
      for (int nt = 0; nt < 4; ++nt) {
        const sx8 bR = *(const sx8*)&rvT[(nt * 16 + lc) * 136 + koff];
        accO[nt] = __builtin_amdgcn_mfma_f32_16x16x32_bf16(aS, bR, accO[nt], 0, 0, 0);
      }
    }
  }

  // write O (C-layout: row = quad*4+e, col = lc, per n-tile)
#pragma unroll
  for (int nt = 0; nt < 4; ++nt) {
#pragma unroll
    for (int e = 0; e < 4; ++e) {
      O[((size_t)(bh * SS + i0 + mt * 16 + quad * 4 + e)) * DD + nt * 16 + lc] = accO[nt][e];
    }
  }
}

extern "C" void kernel_launch(void* const* d_in, const int* in_sizes, int n_in,
                              void* d_out, int out_size, void* d_ws, size_t ws_size,
                              hipStream_t stream) {
  const float* q = (const float*)d_in[0];
  const float* k = (const float*)d_in[1];
  const float* v = (const float*)d_in[2];
  const float* RK = (const float*)d_in[3];  // (1025,64); causal => rows 0..512
  const float* RV = (const float*)d_in[4];

  float* O = (float*)d_out;                         // (B,H,S,D)
  float* W = (float*)d_out + (size_t)BH * SS * DD;  // (B,H,S,S)

  k_logits_mfma<<<dim3(16, BH), 256, 0, stream>>>(q, k, RK, W);
  k_soft_out<<<dim3(16, BH), 256, 0, stream>>>(W, v, RV, O);
}